// Round 4
// baseline (243.943 us; speedup 1.0000x reference)
//
#include <hip/hip_runtime.h>

// PCEN: M_t = (1-s) M_{t-1} + s x_t (IIR along T, T=2048 contiguous per row),
// out = (x*(eps+M)^-alpha + bias)^power - bias^power.
//
// v4: persistent waves + cross-row software pipeline.
// v1/v2/v3 all hit the same 80us wall at 2.5 TB/s with every pipe <35% busy.
// Shared invariant: one row per wave, serial dataflow (all loads -> scan ->
// epilogue -> stores), so each wave alternates memory-only and compute-only
// phases and the memory pipe runs at ~35% duty cycle. fillBuffer sustains
// 6.7 TB/s at 9% occupancy because its waves never stop issuing memory ops.
//
// Here each wave owns RPW=4 consecutive rows and pipelines them:
//   issue loads(row r+1) -> compute row r (scan+epilogue+stores) -> swap.
// Loads precede stores in program order, so the compiler can wait with a
// counted vmcnt (stores still outstanding) instead of a drain; row r's
// ~3k-cycle compute hides row r+1's load latency; the wave keeps 8KB in
// flight continuously. Row loop is "#pragma unroll 1" ON PURPOSE: full
// unroll would hoist all 32 float4 loads and blow registers.
// Stores are non-temporal (output never re-read) so the write stream stops
// evicting the input from L3 (v3: only half the input survived there).

#define T_LEN 2048
#define NCH   8            // chunks per row
#define CHUNK 256          // elems per chunk = 64 lanes * 4
#define RPW   4            // rows per wave

typedef float vfloat4 __attribute__((ext_vector_type(4)));

__device__ __forceinline__ float fast_exp2(float x) { return __builtin_amdgcn_exp2f(x); }
__device__ __forceinline__ float fast_log2(float x) { return __builtin_amdgcn_logf(x); }
__device__ __forceinline__ float readlane63(float v) {
    return __int_as_float(__builtin_amdgcn_readlane(__float_as_int(v), 63));
}

__global__ __launch_bounds__(256, 4) void pcen_kernel(
    const float* __restrict__ x,
    const float* __restrict__ alpha_p,
    const float* __restrict__ power_p,
    const float* __restrict__ bias_p,
    float* __restrict__ out)
{
    const int wave = threadIdx.x >> 6;
    const int lane = threadIdx.x & 63;
    const int gw   = (blockIdx.x << 2) | wave;    // global wave id

    const float alpha = alpha_p[0];
    const float power = power_p[0];
    const float bias  = bias_p[0];

    const float A  = 0.985f;   // 1 - SMOOTH
    const float S  = 0.015f;   // SMOOTH
    const float A2 = A * A;
    const float f4 = A2 * A2;  // A^4: per-segment decay

    // 4 consecutive rows per wave -> contiguous 32KB stream, good L2 locality.
    const float* xr  = x   + (size_t)gw * (RPW * T_LEN) + 4 * lane;
    float*       orw = out + (size_t)gw * (RPW * T_LEN) + 4 * lane;

    // f^lane = A^(4*lane) via 6 select-muls; afterwards t = A^256.
    float fl = 1.0f, t = f4;
#pragma unroll
    for (int b = 1; b < 64; b <<= 1) {
        fl = (lane & b) ? fl * t : fl;
        t *= t;
    }
    const float F = t;         // A^256: whole-chunk decay

    const float bias_pow = fast_exp2(power * fast_log2(bias));
    const float nalpha   = -alpha;

    float4 vc[NCH], vn[NCH];

    // ---- prefetch row 0 ----
#pragma unroll
    for (int c = 0; c < NCH; ++c)
        vc[c] = *reinterpret_cast<const float4*>(xr + c * CHUNK);

#pragma unroll 1
    for (int r = 0; r < RPW; ++r) {
        // ---- issue next row's loads FIRST (before this row's stores) ----
        if (r + 1 < RPW) {
#pragma unroll
            for (int c = 0; c < NCH; ++c)
                vn[c] = *reinterpret_cast<const float4*>(
                            xr + (size_t)(r + 1) * T_LEN + c * CHUNK);
        }

        // ---- lane-local scans (carry-free): segment end-state per chunk ----
        float s[NCH];
#pragma unroll
        for (int c = 0; c < NCH; ++c) {
            float m = 0.0f;
            m = fmaf(A, m, S * vc[c].x);
            m = fmaf(A, m, S * vc[c].y);
            m = fmaf(A, m, S * vc[c].z);
            m = fmaf(A, m, S * vc[c].w);
            s[c] = m;
        }

        // ---- Kogge-Stone inclusive scans, 8 chunks interleaved per step ----
        {
            float g = f4;
#pragma unroll
            for (int d = 1; d < 64; d <<= 1) {
#pragma unroll
                for (int c = 0; c < NCH; ++c) {
                    const float so = __shfl_up(s[c], d, 64);
                    if (lane >= d) s[c] = fmaf(g, so, s[c]);
                }
                g *= g;
            }
        }

        // ---- apply carries + epilogue + streaming stores, chunk by chunk ----
        float R = 0.0f;        // absolute M at end of previous chunk (uniform)
#pragma unroll
        for (int c = 0; c < NCH; ++c) {
            float e = __shfl_up(s[c], 1, 64);
            if (lane == 0) e = 0.0f;
            const float s63 = readlane63(s[c]);
            float M = fmaf(fl, R, e);     // abs M before this lane's elem 0
            R = fmaf(F, R, s63);          // advance uniform chunk carry

            vfloat4 w;
#pragma unroll
            for (int j = 0; j < 4; ++j) {
                const float xj = (j == 0) ? vc[c].x : (j == 1) ? vc[c].y
                               : (j == 2) ? vc[c].z : vc[c].w;
                M = fmaf(A, M, S * xj);
                const float den = 1e-9f + M;
                const float tt  = fmaf(xj, fast_exp2(nalpha * fast_log2(den)), bias);
                w[j] = fast_exp2(power * fast_log2(tt)) - bias_pow;
            }
            __builtin_nontemporal_store(
                w, reinterpret_cast<vfloat4*>(orw + (size_t)r * T_LEN + c * CHUNK));
        }

        // ---- rotate buffers (8x4 v_movs; compiler renames most away) ----
        if (r + 1 < RPW) {
#pragma unroll
            for (int c = 0; c < NCH; ++c) vc[c] = vn[c];
        }
    }
}

extern "C" void kernel_launch(void* const* d_in, const int* in_sizes, int n_in,
                              void* d_out, int out_size, void* d_ws, size_t ws_size,
                              hipStream_t stream) {
    const float* x       = (const float*)d_in[0];
    const float* alpha_p = (const float*)d_in[1];
    const float* power_p = (const float*)d_in[2];
    const float* bias_p  = (const float*)d_in[3];
    float* out           = (float*)d_out;

    const int nrows  = in_sizes[0] / T_LEN;       // 16384
    const int blocks = nrows / (4 * RPW);         // 4 waves/block, RPW rows/wave

    pcen_kernel<<<blocks, 256, 0, stream>>>(x, alpha_p, power_p, bias_p, out);
}

// Round 5
// 240.819 us; speedup vs baseline: 1.0130x; 1.0130x over previous
//
#include <hip/hip_runtime.h>

// PCEN: M_t = (1-s) M_{t-1} + s x_t (IIR along T, T=2048 contiguous per row),
// out = (x*(eps+M)^-alpha + bias)^power - bias^power.
//
// v5: v3 structure (best measured: 80.0us, 32 VGPR, 64% occ) with TWO rows
// fully interleaved per wave in straight-line code.
// Rationale: rounds 0-4 proved the 80us wall is insensitive to occupancy,
// coalescing, LDS/barriers, and sequential cross-row pipelining (v4's
// rotate-buffer variant regressed: its vmcnt waits counted in-flight stores).
// All versions shared one trait: each wave alternates all-or-nothing phases
// (wait-all-loads -> 6-step dependent shuffle scan -> trans epilogue ->
// store burst), so issue density within a wave is low and identically-phased
// waves stay burst-correlated. Interleaving 2 INDEPENDENT rows doubles
// issue density in every phase at zero extra serial depth:
//   - 16 upfront loads (2 rows x 8 chunks), all independent;
//   - Kogge-Stone: 6 steps, 16 independent shuffles/step (shared g);
//   - epilogue: 2 independent trans-chains interleaved by the scheduler;
//   - stores of both rows interleave through the latency windows.
// No buffer rotation, no nt-stores (v4 showed no FETCH benefit). ~100 VGPR
// -> __launch_bounds__(256,4).

#define T_LEN 2048
#define NCH   8            // chunks per row
#define CHUNK 256          // elems per chunk = 64 lanes * 4
#define RPW   2            // rows per wave, interleaved

__device__ __forceinline__ float fast_exp2(float x) { return __builtin_amdgcn_exp2f(x); }
__device__ __forceinline__ float fast_log2(float x) { return __builtin_amdgcn_logf(x); }
__device__ __forceinline__ float readlane63(float v) {
    return __int_as_float(__builtin_amdgcn_readlane(__float_as_int(v), 63));
}

__global__ __launch_bounds__(256, 4) void pcen_kernel(
    const float* __restrict__ x,
    const float* __restrict__ alpha_p,
    const float* __restrict__ power_p,
    const float* __restrict__ bias_p,
    float* __restrict__ out)
{
    const int wave = threadIdx.x >> 6;
    const int lane = threadIdx.x & 63;
    const int gw   = (blockIdx.x << 2) | wave;    // global wave id

    const float alpha = alpha_p[0];
    const float power = power_p[0];
    const float bias  = bias_p[0];

    const float A  = 0.985f;   // 1 - SMOOTH
    const float S  = 0.015f;   // SMOOTH
    const float A2 = A * A;
    const float f4 = A2 * A2;  // A^4: per-segment decay

    // two consecutive rows per wave
    const float* xr0 = x   + (size_t)gw * (RPW * T_LEN) + 4 * lane;
    const float* xr1 = xr0 + T_LEN;
    float*       ow0 = out + (size_t)gw * (RPW * T_LEN) + 4 * lane;
    float*       ow1 = ow0 + T_LEN;

    // ---- issue ALL 16 loads upfront (2 rows x 8 contiguous 1KB wave-loads) ----
    float4 v0[NCH], v1[NCH];
#pragma unroll
    for (int c = 0; c < NCH; ++c) {
        v0[c] = *reinterpret_cast<const float4*>(xr0 + c * CHUNK);
        v1[c] = *reinterpret_cast<const float4*>(xr1 + c * CHUNK);
    }

    // ---- f^lane = A^(4*lane) via 6 select-muls; afterwards t = A^256 ----
    float fl = 1.0f, t = f4;
#pragma unroll
    for (int b = 1; b < 64; b <<= 1) {
        fl = (lane & b) ? fl * t : fl;
        t *= t;
    }
    const float F = t;         // A^256: whole-chunk decay

    const float bias_pow = fast_exp2(power * fast_log2(bias));
    const float nalpha   = -alpha;

    // ---- lane-local scans (carry-free): 16 independent 4-deep chains ----
    float s0[NCH], s1[NCH];
#pragma unroll
    for (int c = 0; c < NCH; ++c) {
        float m0 = 0.0f, m1 = 0.0f;
        m0 = fmaf(A, m0, S * v0[c].x);  m1 = fmaf(A, m1, S * v1[c].x);
        m0 = fmaf(A, m0, S * v0[c].y);  m1 = fmaf(A, m1, S * v1[c].y);
        m0 = fmaf(A, m0, S * v0[c].z);  m1 = fmaf(A, m1, S * v1[c].z);
        m0 = fmaf(A, m0, S * v0[c].w);  m1 = fmaf(A, m1, S * v1[c].w);
        s0[c] = m0; s1[c] = m1;
    }

    // ---- Kogge-Stone: 6 steps, 16 independent shuffles per step ----
    {
        float g = f4;
#pragma unroll
        for (int d = 1; d < 64; d <<= 1) {
#pragma unroll
            for (int c = 0; c < NCH; ++c) {
                const float a0 = __shfl_up(s0[c], d, 64);
                const float a1 = __shfl_up(s1[c], d, 64);
                if (lane >= d) {
                    s0[c] = fmaf(g, a0, s0[c]);
                    s1[c] = fmaf(g, a1, s1[c]);
                }
            }
            g *= g;
        }
    }

    // ---- carries + epilogue + stores, both rows interleaved per chunk ----
    float R0 = 0.0f, R1 = 0.0f;   // abs M at end of previous chunk (uniform)
#pragma unroll
    for (int c = 0; c < NCH; ++c) {
        float e0 = __shfl_up(s0[c], 1, 64);
        float e1 = __shfl_up(s1[c], 1, 64);
        if (lane == 0) { e0 = 0.0f; e1 = 0.0f; }
        const float x0 = readlane63(s0[c]);
        const float x1 = readlane63(s1[c]);
        float M0 = fmaf(fl, R0, e0);     // abs M before this lane's elem 0
        float M1 = fmaf(fl, R1, e1);
        R0 = fmaf(F, R0, x0);            // advance uniform chunk carries
        R1 = fmaf(F, R1, x1);

        float4 r0, r1;
#pragma unroll
        for (int j = 0; j < 4; ++j) {
            const float xj0 = (j == 0) ? v0[c].x : (j == 1) ? v0[c].y
                            : (j == 2) ? v0[c].z : v0[c].w;
            const float xj1 = (j == 0) ? v1[c].x : (j == 1) ? v1[c].y
                            : (j == 2) ? v1[c].z : v1[c].w;
            M0 = fmaf(A, M0, S * xj0);
            M1 = fmaf(A, M1, S * xj1);
            const float t0 = fmaf(xj0, fast_exp2(nalpha * fast_log2(1e-9f + M0)), bias);
            const float t1 = fmaf(xj1, fast_exp2(nalpha * fast_log2(1e-9f + M1)), bias);
            const float r0j = fast_exp2(power * fast_log2(t0)) - bias_pow;
            const float r1j = fast_exp2(power * fast_log2(t1)) - bias_pow;
            if (j == 0) { r0.x = r0j; r1.x = r1j; }
            else if (j == 1) { r0.y = r0j; r1.y = r1j; }
            else if (j == 2) { r0.z = r0j; r1.z = r1j; }
            else { r0.w = r0j; r1.w = r1j; }
        }
        *reinterpret_cast<float4*>(ow0 + c * CHUNK) = r0;   // contiguous 1KB
        *reinterpret_cast<float4*>(ow1 + c * CHUNK) = r1;
    }
}

extern "C" void kernel_launch(void* const* d_in, const int* in_sizes, int n_in,
                              void* d_out, int out_size, void* d_ws, size_t ws_size,
                              hipStream_t stream) {
    const float* x       = (const float*)d_in[0];
    const float* alpha_p = (const float*)d_in[1];
    const float* power_p = (const float*)d_in[2];
    const float* bias_p  = (const float*)d_in[3];
    float* out           = (float*)d_out;

    const int nrows  = in_sizes[0] / T_LEN;       // 16384
    const int blocks = nrows / (4 * RPW);         // 4 waves/block, 2 rows/wave

    pcen_kernel<<<blocks, 256, 0, stream>>>(x, alpha_p, power_p, bias_p, out);
}